// Round 4
// baseline (1070.028 us; speedup 1.0000x reference)
//
#include <hip/hip_runtime.h>
#include <math.h>

#define ATTN_SCALE 0.07216878364870322f  // 192^-0.5

typedef __attribute__((ext_vector_type(8))) short short8;
typedef __attribute__((ext_vector_type(4))) float floatx4;

__device__ __forceinline__ unsigned short f2bf(float f) {
    union { float f; unsigned int u; } v; v.f = f;
    unsigned int r = v.u + 0x7fffu + ((v.u >> 16) & 1u);
    return (unsigned short)(r >> 16);
}
__device__ __forceinline__ float bf2f(unsigned short h) {
    union { unsigned int u; float f; } v; v.u = ((unsigned int)h) << 16;
    return v.f;
}
__device__ __forceinline__ void gld16(const void* g, void* l) {
    __builtin_amdgcn_global_load_lds(
        (const __attribute__((address_space(1))) unsigned int*)g,
        (__attribute__((address_space(3))) unsigned int*)l, 16, 0, 0);
}

// ---------------- RMSNorm fp32 in -> bf16 out ----------------
__global__ __launch_bounds__(256) void rms_kernel(
    const float* __restrict__ in, int ld_in,
    const float* __restrict__ w,
    unsigned short* __restrict__ out, int ld_out, int N)
{
    const int row = blockIdx.x;
    const int tid = threadIdx.x;
    const float* x = in + (size_t)row * ld_in;
    float ss = 0.f;
    for (int i = tid * 4; i < N; i += 1024) {
        float4 v = *(const float4*)(x + i);
        ss += v.x * v.x + v.y * v.y + v.z * v.z + v.w * v.w;
    }
    #pragma unroll
    for (int off = 32; off > 0; off >>= 1)
        ss += __shfl_down(ss, off);
    __shared__ float red[4];
    const int lane = tid & 63, wid = tid >> 6;
    if (lane == 0) red[wid] = ss;
    __syncthreads();
    const float tot = red[0] + red[1] + red[2] + red[3];
    const float rs = rsqrtf(tot / (float)N + 1e-6f);
    unsigned short* o = out + (size_t)row * ld_out;
    for (int i = tid * 4; i < N; i += 1024) {
        float4 v = *(const float4*)(x + i);
        float4 wv = *(const float4*)(w + i);
        __align__(8) unsigned short ov[4];
        ov[0] = f2bf(v.x * rs * wv.x);
        ov[1] = f2bf(v.y * rs * wv.y);
        ov[2] = f2bf(v.z * rs * wv.z);
        ov[3] = f2bf(v.w * rs * wv.w);
        *(uint2*)&o[i] = *(uint2*)ov;
    }
}

// ---------------- weight cast+transpose: W fp32[K,N] -> Wt bf16[Npad,K] ----------------
__global__ __launch_bounds__(256) void cast_transpose_kernel(
    const float* __restrict__ W, unsigned short* __restrict__ Wt,
    int K, int N)
{
    __shared__ float tile[64][65];
    const int tid = threadIdx.x;
    const int kb = blockIdx.y * 64;
    const int nb = blockIdx.x * 64;
    const int r  = tid >> 2;
    const int c0 = (tid & 3) * 16;
    if (nb + 64 <= N) {
        #pragma unroll
        for (int j = 0; j < 16; j += 4)
            *(float4*)&tile[r][c0 + j] =
                *(const float4*)&W[(size_t)(kb + r) * N + nb + c0 + j];
    } else {
        for (int j = 0; j < 16; ++j) {
            int n = nb + c0 + j;
            tile[r][c0 + j] = (n < N) ? W[(size_t)(kb + r) * N + n] : 0.f;
        }
    }
    __syncthreads();
    __align__(16) unsigned short ov[16];
    #pragma unroll
    for (int j = 0; j < 16; ++j) ov[j] = f2bf(tile[c0 + j][r]);
    int4* dst = (int4*)&Wt[(size_t)(nb + r) * K + kb + c0];
    dst[0] = ((int4*)ov)[0];
    dst[1] = ((int4*)ov)[1];
}

// ---------------- bf16 MFMA GEMM 128-tile (kept for small shapes) ----------------
__global__ __launch_bounds__(256) void gemm_bf16_kernel(
    const unsigned short* __restrict__ A,   // [M,K] bf16
    const unsigned short* __restrict__ Bt,  // [Npad,K] bf16
    float* __restrict__ C,                  // fp32 out (or null)
    unsigned short* __restrict__ Cb,        // bf16 out (or null)
    const float* __restrict__ R,            // fp32 residual (or null)
    int N, int K)
{
    __shared__ __align__(16) unsigned short As[2][4096];
    __shared__ __align__(16) unsigned short Bs[2][4096];
    const int tid = threadIdx.x;
    const int w  = tid >> 6;
    const int l  = tid & 63;
    const int lm = l & 15;
    const int lk = l >> 4;
    const int row0 = blockIdx.y * 128;
    const int col0 = blockIdx.x * 128;
    const int wm = (w >> 1) * 64;
    const int wn = (w & 1) * 64;
    const int nsplit = gridDim.z;
    const int kz = blockIdx.z;
    const int kchunk = K / nsplit;
    const int kbase = kz * kchunk;

    const unsigned short* a0 = A  + (size_t)(row0 + w * 16 + lm) * K + kbase + lk * 8;
    const unsigned short* a1 = a0 + (size_t)64 * K;
    const unsigned short* b0 = Bt + (size_t)(col0 + w * 16 + lm) * K + kbase + lk * 8;
    const unsigned short* b1 = b0 + (size_t)64 * K;
    const int s0 = w * 512 + l * 8;
    const int s1 = (w + 4) * 512 + l * 8;

    floatx4 acc[4][4];
    #pragma unroll
    for (int i = 0; i < 4; ++i)
        #pragma unroll
        for (int j = 0; j < 4; ++j)
            acc[i][j] = (floatx4){0.f, 0.f, 0.f, 0.f};

    gld16(a0, &As[0][s0]);
    gld16(a1, &As[0][s1]);
    gld16(b0, &Bs[0][s0]);
    gld16(b1, &Bs[0][s1]);
    a0 += 32; a1 += 32; b0 += 32; b1 += 32;
    __syncthreads();

    const int niter = kchunk >> 5;
    int cur = 0;
    for (int t = 0; t < niter; ++t) {
        if (t + 1 < niter) {
            gld16(a0, &As[cur ^ 1][s0]);
            gld16(a1, &As[cur ^ 1][s1]);
            gld16(b0, &Bs[cur ^ 1][s0]);
            gld16(b1, &Bs[cur ^ 1][s1]);
            a0 += 32; a1 += 32; b0 += 32; b1 += 32;
        }
        short8 af[4], bg_[4];
        #pragma unroll
        for (int i = 0; i < 4; ++i)
            af[i] = *(const short8*)&As[cur][((w >> 1) * 4 + i) * 512 + l * 8];
        #pragma unroll
        for (int j = 0; j < 4; ++j)
            bg_[j] = *(const short8*)&Bs[cur][((w & 1) * 4 + j) * 512 + l * 8];
        #pragma unroll
        for (int i = 0; i < 4; ++i)
            #pragma unroll
            for (int j = 0; j < 4; ++j)
                acc[i][j] = __builtin_amdgcn_mfma_f32_16x16x32_bf16(
                    af[i], bg_[j], acc[i][j], 0, 0, 0);
        __syncthreads();
        cur ^= 1;
    }

    const int quad = l >> 4;
    const bool ng = (col0 + 128 > N);
    #pragma unroll
    for (int i = 0; i < 4; ++i) {
        #pragma unroll
        for (int r = 0; r < 4; ++r) {
            const int m = row0 + wm + i * 16 + quad * 4 + r;
            #pragma unroll
            for (int j = 0; j < 4; ++j) {
                const int n = col0 + wn + j * 16 + lm;
                if (ng && n >= N) continue;
                const size_t off = (size_t)m * N + n;
                float v = acc[i][j][r];
                if (nsplit > 1) {
                    if (R && kz == 0) v += R[off];
                    unsafeAtomicAdd(&C[off], v);
                } else if (Cb) {
                    Cb[off] = f2bf(v);
                } else {
                    if (R) v += R[off];
                    C[off] = v;
                }
            }
        }
    }
}

// ---------------- bf16 MFMA GEMM 256-tile, 4-phase fine interleave per K-tile ----------------
// 512 threads = 8 waves (2M x 4N), per-wave C = 128x64, BK=64, LDS 128 KB dbuf.
// Per K-tile: 4 phases, phase q = { ds_read A-quadrant q (+ all B frags in q0),
//   stage 4 gld16 of tile t+1 in q0/q1 -> buf[p^1], s_barrier, setprio(1),
//   16 MFMA, setprio(0), s_barrier }. One vmcnt(0) per tile at the boundary;
// stages issued in q0/q1 get ~2.5 phases of latency cover. buf[p^1] is never
// read during tile t -> staging is race-free; barriers are uniform.
__global__ __launch_bounds__(512) void gemm256_kernel(
    const unsigned short* __restrict__ A,   // [M,K] bf16
    const unsigned short* __restrict__ Bt,  // [N,K] bf16
    float* __restrict__ C,                  // fp32 out (or null)
    unsigned short* __restrict__ Cb,        // bf16 out (or null)
    const float* __restrict__ R,            // fp32 residual (or null)
    int N, int K)
{
    __shared__ __align__(16) unsigned short As[2][16384];  // 2 x 32 KB
    __shared__ __align__(16) unsigned short Bs[2][16384];  // 2 x 32 KB
    const int tid = threadIdx.x;
    const int w   = tid >> 6;
    const int l   = tid & 63;
    const int lm  = l & 15;
    const int quad = l >> 4;
    const int wm2 = w >> 2;   // 0..1
    const int wn4 = w & 3;    // 0..3

    // XCD-aware bijective swizzle of flat (y,x) id (T1, m204 variant)
    const int gx = gridDim.x;
    const int nwg = gx * gridDim.y;
    int bid = blockIdx.y * gx + blockIdx.x;
    {
        const int q = nwg >> 3, r = nwg & 7;
        const int xcd = bid & 7, off = bid >> 3;
        bid = (xcd < r ? xcd * (q + 1) : r * (q + 1) + (xcd - r) * q) + off;
    }
    const int row0 = (bid / gx) * 256;
    const int col0 = (bid % gx) * 256;

    const int nsplit = gridDim.z;
    const int kz = blockIdx.z;
    const int kchunk = K / nsplit;
    const int kbase = kz * kchunk;

    // staging: thread stages 16B unit u = j*512 + tid (j=0..3) per matrix per K-tile
    const int slk = (tid >> 4) & 7;     // k-subchunk 0..7
    const int srg = tid >> 7;           // row-subgroup 0..3
    const unsigned short* sa = A  + (size_t)(row0 + srg * 16 + lm) * K + kbase + slk * 8;
    const unsigned short* sb = Bt + (size_t)(col0 + srg * 16 + lm) * K + kbase + slk * 8;

    floatx4 acc[8][4];
    #pragma unroll
    for (int i = 0; i < 8; ++i)
        #pragma unroll
        for (int j = 0; j < 4; ++j)
            acc[i][j] = (floatx4){0.f, 0.f, 0.f, 0.f};

    const int nt = kchunk >> 6;
    // prologue: stage K-tile 0 into buffer 0 (8 global_load_lds per thread)
    #pragma unroll
    for (int j = 0; j < 4; ++j) {
        gld16(sa + (size_t)j * 64 * K, (char*)As[0] + j * 8192 + tid * 16);
        gld16(sb + (size_t)j * 64 * K, (char*)Bs[0] + j * 8192 + tid * 16);
    }
    asm volatile("s_waitcnt vmcnt(0)" ::: "memory");
    __builtin_amdgcn_sched_barrier(0);
    __builtin_amdgcn_s_barrier();
    __builtin_amdgcn_sched_barrier(0);

    for (int t = 0; t < nt; ++t) {
        const int p = t & 1;
        const char* ab = (const char*)As[p] + wm2 * 16384 + l * 16;
        const char* bb = (const char*)Bs[p] + wn4 * 8192  + l * 16;
        char* dA = (char*)As[p ^ 1] + tid * 16;
        char* dB = (char*)Bs[p ^ 1] + tid * 16;
        const size_t ko = (size_t)(t + 1) * 64;
        const bool pre = (t + 1 < nt);
        short8 bfr[4][2];
        short8 afr[2][2];

        #pragma unroll
        for (int q = 0; q < 4; ++q) {
            // ---- ds-load register subtiles for this phase ----
            if (q == 0) {
                #pragma unroll
                for (int j = 0; j < 4; ++j) {
                    bfr[j][0] = *(const short8*)(bb + j * 2048);
                    bfr[j][1] = *(const short8*)(bb + j * 2048 + 1024);
                }
            }
            afr[0][0] = *(const short8*)(ab + (2 * q) * 2048);
            afr[0][1] = *(const short8*)(ab + (2 * q) * 2048 + 1024);
            afr[1][0] = *(const short8*)(ab + (2 * q + 1) * 2048);
            afr[1][1] = *(const short8*)(ab + (2 * q + 1) * 2048 + 1024);
            // ---- stage next K-tile (phases 0 and 1 only) ----
            if (pre) {
                if (q == 0) {
                    gld16(sa + ko, dA);
                    gld16(sb + ko, dB);
                    gld16(sa + (size_t)64 * K + ko, dA + 8192);
                    gld16(sb + (size_t)64 * K + ko, dB + 8192);
                } else if (q == 1) {
                    gld16(sa + (size_t)128 * K + ko, dA + 16384);
                    gld16(sb + (size_t)128 * K + ko, dB + 16384);
                    gld16(sa + (size_t)192 * K + ko, dA + 24576);
                    gld16(sb + (size_t)192 * K + ko, dB + 24576);
                }
            }
            __builtin_amdgcn_sched_barrier(0);
            __builtin_amdgcn_s_barrier();
            __builtin_amdgcn_sched_barrier(0);
            // ---- MFMA cluster: quadrant q (i = 2q, 2q+1) x all j x K=64 ----
            __builtin_amdgcn_s_setprio(1);
            #pragma unroll
            for (int c = 0; c < 2; ++c)
                #pragma unroll
                for (int i2 = 0; i2 < 2; ++i2)
                    #pragma unroll
                    for (int j = 0; j < 4; ++j)
                        acc[2 * q + i2][j] = __builtin_amdgcn_mfma_f32_16x16x32_bf16(
                            afr[i2][c], bfr[j][c], acc[2 * q + i2][j], 0, 0, 0);
            __builtin_amdgcn_s_setprio(0);
            __builtin_amdgcn_sched_barrier(0);
            if (q == 3)
                asm volatile("s_waitcnt vmcnt(0)" ::: "memory");  // tile t+1 landed
            __builtin_amdgcn_s_barrier();
            __builtin_amdgcn_sched_barrier(0);
        }
    }

    #pragma unroll
    for (int i = 0; i < 8; ++i) {
        #pragma unroll
        for (int r = 0; r < 4; ++r) {
            const int m = row0 + wm2 * 128 + i * 16 + quad * 4 + r;
            #pragma unroll
            for (int j = 0; j < 4; ++j) {
                const int n = col0 + wn4 * 64 + j * 16 + lm;
                const size_t off = (size_t)m * N + n;
                float v = acc[i][j][r];
                if (nsplit > 1) {
                    if (R && kz == 0) v += R[off];
                    unsafeAtomicAdd(&C[off], v);
                } else if (Cb) {
                    Cb[off] = f2bf(v);
                } else {
                    if (R) v += R[off];
                    C[off] = v;
                }
            }
        }
    }
}

// ---------------- RoPE on bf16 q (in place, interleave -> half) ----------------
__global__ __launch_bounds__(256) void rope_q_kernel(
    unsigned short* __restrict__ x,
    const float* __restrict__ cosb, const float* __restrict__ sinb,
    const int* __restrict__ pos_ids)
{
    const int gid = blockIdx.x * 256 + threadIdx.x;
    const int i = gid & 31;
    const int grp = gid >> 5;
    const int hh = grp & 15;
    const int row = grp >> 4;
    unsigned short* base = x + (size_t)row * 3072 + hh * 192 + 128;
    const float x0 = bf2f(base[2 * i]);
    const float x1 = bf2f(base[2 * i + 1]);
    const int p = pos_ids[row];
    const float c = cosb[p * 64 + i];
    const float s = sinb[p * 64 + i];
    __syncthreads();
    base[i]      = f2bf(x0 * c - x1 * s);
    base[32 + i] = f2bf(x1 * c + x0 * s);
}

// ---------------- RoPE k_pe: ckv fp32 cols 512.. -> kpe bf16 [2048][64] ----------------
__global__ __launch_bounds__(256) void rope_kpe_kernel(
    const float* __restrict__ ckv, unsigned short* __restrict__ kpe,
    const float* __restrict__ cosb, const float* __restrict__ sinb,
    const int* __restrict__ pos_ids)
{
    const int gid = blockIdx.x * 256 + threadIdx.x;
    const int i = gid & 31;
    const int row = gid >> 5;
    const float x0 = ckv[(size_t)row * 576 + 512 + 2 * i];
    const float x1 = ckv[(size_t)row * 576 + 512 + 2 * i + 1];
    const int p = pos_ids[row];
    const float c = cosb[p * 64 + i];
    const float s = sinb[p * 64 + i];
    kpe[(size_t)row * 64 + i]      = f2bf(x0 * c - x1 * s);
    kpe[(size_t)row * 64 + 32 + i] = f2bf(x1 * c + x0 * s);
}

// ---------------- V transpose: kvb bf16 -> vtg[16][128][2048] bf16 ----------------
__global__ __launch_bounds__(256) void vtrans_kernel(
    const unsigned short* __restrict__ kvb, unsigned short* __restrict__ vtg)
{
    __shared__ unsigned short tile[64][72];
    const int tid = threadIdx.x;
    const int s0 = blockIdx.x * 64;
    const int d0 = blockIdx.y * 64;
    const int h  = blockIdx.z;
    const int r  = tid >> 2;
    const int c0 = (tid & 3) * 16;
    *(int4*)&tile[r][c0] =
        *(const int4*)&kvb[(size_t)(s0 + r) * 4096 + h * 256 + 128 + d0 + c0];
    *(int4*)&tile[r][c0 + 8] =
        *(const int4*)&kvb[(size_t)(s0 + r) * 4096 + h * 256 + 128 + d0 + c0 + 8];
    __syncthreads();
    __align__(16) unsigned short ov[16];
    #pragma unroll
    for (int j = 0; j < 16; ++j) ov[j] = tile[c0 + j][r];
    unsigned short* dst = vtg + ((size_t)(h * 128 + d0 + r)) * 2048 + s0 + c0;
    ((int4*)dst)[0] = ((int4*)ov)[0];
    ((int4*)dst)[1] = ((int4*)ov)[1];
}

// ---------------- MFMA flash attention ----------------
__global__ __launch_bounds__(512) void attn_mfma_kernel(
    const unsigned short* __restrict__ qb,   // [2048][3072] bf16 (roped)
    const unsigned short* __restrict__ kvb,  // [2048][4096] bf16
    const unsigned short* __restrict__ kpe,  // [2048][64] bf16 (roped)
    const unsigned short* __restrict__ vtg,  // [16][128][2048] bf16
    unsigned short* __restrict__ out)        // [2048][2048] bf16
{
    __shared__ __align__(16) unsigned short Kf[128 * 200];   // 51200 B, row stride 400 B
    __shared__ __align__(16) unsigned short Vt[2][128 * 136];// 2x34816 B, row stride 272 B
    __shared__ __align__(16) unsigned short Ps[64 * 136];    // 17408 B
    __shared__ float pmax_s[8][64];
    __shared__ float psum_s[8][64];
    __shared__ __align__(16) float m_state[64];
    __shared__ __align__(16) float l_state[64];
    __shared__ __align__(16) float alpha_s[64];
    __shared__ __align__(16) float mnew_s[64];

    const int tid  = threadIdx.x;
    const int w    = tid >> 6;
    const int l    = tid & 63;
    const int l15  = l & 15;
    const int quad = l >> 4;
    const int h    = blockIdx.y;
    const int qs   = (w & 3) * 16;   // PV q strip
    const int dh   = (w >> 2) * 64;  // PV d half

    for (int pass = 0; pass < 2; ++pass) {
        const int qt = pass ? (31 - (int)blockIdx.x) : (int)blockIdx.x;
        const int q0 = qt * 64;
        const int ntiles = (qt >> 1) + 1;

        short8 qf[4][6];
        #pragma unroll
        for (int nt = 0; nt < 4; ++nt)
            #pragma unroll
            for (int c = 0; c < 6; ++c)
                qf[nt][c] = *(const short8*)&qb[(size_t)(q0 + nt * 16 + l15) * 3072
                                               + h * 192 + c * 32 + quad * 8];

        floatx4 oacc[4];
        #pragma unroll
        for (int nt = 0; nt < 4; ++nt) oacc[nt] = (floatx4){0.f, 0.f, 0.f, 0.f};
        if (tid < 64) { m_state[tid] = -3e38f; l_state[tid] = 0.f; }

        // stage tile 0
        {
            const int k0 = 0;
            for (int s = w; s < 50; s += 8) {
                unsigned ab = s * 1024 + l * 16;
                unsigned row = ab / 400u;
                unsigned g = (ab - row * 400u) >> 4;
                const unsigned short* src;
                if (g < 16u)      src = kvb + (size_t)(k0 + row) * 4096 + h * 256 + g * 8;
                else if (g < 24u) src = kpe + (size_t)(k0 + row) * 64 + (g - 16u) * 8;
                else              src = kpe + (size_t)(k0 + row) * 64;
                gld16(src, (char*)Kf + ab);
            }
            for (int s = w; s < 34; s += 8) {
                unsigned ab = s * 1024 + l * 16;
                unsigned row = ab / 272u;
                unsigned g = (ab - row * 272u) >> 4;
                const unsigned short* src =
                    vtg + (size_t)(h * 128 + row) * 2048 + k0 + (g < 16u ? g * 8 : 0u);
                gld16(src, (char*)Vt[0] + ab);
            }
        }

        for (int kt = 0; kt < ntiles; ++kt) {
            const int k0 = kt * 128;
            const int vb = kt & 1;
            __syncthreads();  // staging of kt complete; prev-iter LDS reads done

            // ---- QK^T ----
            floatx4 st[4];
            #pragma unroll
            for (int nt = 0; nt < 4; ++nt) st[nt] = (floatx4){0.f, 0.f, 0.f, 0.f};
            #pragma unroll
            for (int c = 0; c < 6; ++c) {
                short8 kf = *(const short8*)&Kf[(w * 16 + l15) * 200 + c * 32 + quad * 8];
                #pragma unroll
                for (int nt = 0; nt < 4; ++nt)
                    st[nt] = __builtin_amdgcn_mfma_f32_16x16x32_bf16(kf, qf[nt][c], st[nt], 0, 0, 0);
            }
            #pragma unroll
            for (int nt = 0; nt < 4; ++nt) {
                const int qq = q0 + nt * 16 + l15;
                float vmax = -3e38f;
                #pragma unroll
                for (int r = 0; r < 4; ++r) {
                    const int kpos = k0 + w * 16 + quad * 4 + r;
                    float v = st[nt][r] * ATTN_SCALE;
                    if (kpos > qq) v = -3e38f;
                    st[nt][r] = v;
                    vmax = fmaxf(vmax, v);
                }
                vmax = fmaxf(vmax, __shfl_xor(vmax, 16));
                vmax = fmaxf(vmax, __shfl_xor(vmax, 32));
                if (quad == 0) pmax_s[w][nt * 16 + l15] = vmax;
            }
            __syncthreads();
            if (tid < 64) {
                float mp = m_state[tid];
                float mn = mp;
                #pragma unroll
                for (int ww = 0; ww < 8; ++ww) mn = fmaxf(mn, pmax_s[ww][tid]);
                alpha_s[tid] = __expf(mp - mn);
                mnew_s[tid] = mn;
                m_state[tid] = mn;
            }
            __syncthreads();

            // ---- p = exp(s - m), pack -> Ps, col sums ----
            #pragma unroll
            for (int nt = 0; nt < 4; ++nt) {
                const float mn = mnew_s[nt * 16 + l15];
                float vsum = 0.f;
                __align__(8) unsigned short pb[4];
                #pragma unroll
                for (int r = 0; r < 4; ++r) {
                    float p = __expf(st[nt][r] - mn);
                    vsum += p;
                    pb[r] = f2bf(p);
                }
                *(uint2*)&Ps[(nt * 16 + l15) * 136 + w * 16 + quad * 4] = *(uint2*)pb;
                vsum += __shfl_xor(vsum, 16);
                vsum += __shfl_xor(vsum, 32);
                if (quad == 0) psum_s[w][nt * 16 + l15] = vsum;
            }
            {
                float4 al4 = *(const float4*)&alpha_s[qs + quad * 4];
                #pragma unroll
                for (int nt = 0; nt < 4; ++nt) {
                    oacc[nt][0] *= al4.x; oacc[nt][1] *= al4.y;
                    oacc[nt][2] *= al4.z; oacc[nt][3] *= al4.w;
                }
            }
            __syncthreads();
            if (tid < 64) {
                float acc = 0.f;
                #pragma unroll
                for (int ww = 0; ww < 8; ++ww) acc += psum_s[ww][tid];
                l_state[tid] = l_state[tid] * alpha_s[tid] + acc;
            }
            if (kt + 1 < ntiles) {
                const int k1 = k0 + 128;
                for (int s = w; s < 50; s += 8) {
                    unsigned ab = s * 1024 + l * 16;
                    unsigned row = ab / 400u;
                    unsigned g = (ab - row * 400u) >> 4;
                    const unsigned short* src;
                    if (g < 16u)      src = kvb + (size_t)(k1 + row) * 4096 + h * 256 + g * 8;
                    else if (g < 24u) src = kpe + (size_t)(k1 + row) * 64 + (g - 16u) * 8;
                    else              src = kpe + (size_t)(k1 + row) * 64;
                    gld16(src, (char*)Kf + ab);
                }
                for (int s = w; s < 34; s += 8) {
                    unsigned ab = s * 1024 + l * 16;
                    unsigned row = ab / 272u;
                    unsigned g = (ab - row * 272u) >> 4;
                    const unsigned short* src =
                        vtg + (size_t)(h * 128 + row) * 2048 + k1 + (g < 16u ? g * 8 : 0u);
                    gld16(src, (char*)Vt[vb ^ 1] + ab);
                }
            }
            // ---- PV ----
            #pragma unroll
            for (int c = 0; c < 4; ++c) {
                short8 pf = *(const short8*)&Ps[(qs + l15) * 136 + c * 32 + quad * 8];
                #pragma unroll
                for (int nt = 0; nt < 4; ++nt) {
                    short8 vf = *(const short8*)&Vt[vb][(dh + nt * 16 + l15) * 136
                                                       + c * 32 + quad * 8];
                    oacc[nt] = __builtin_amdgcn_mfma_f32_16x16x32_bf16(pf, vf, oacc[nt], 0, 0, 0);
                }
            }
        }
        __syncthreads();

        // ---- epilogue ----
        {
            float4 l4 = *(const float4*)&l_state[qs + quad * 4];
            float inv0 = 1.f / l4.x, inv1 = 1.f / l4.y, inv2 = 1.f / l4.z, inv3 = 1.f / l4.w;
            #pragma unroll
            for (int nt = 0; nt < 4; ++nt) {
                const size_t col = h * 128 + dh + nt * 16 + l15;
                out[(size_t)(q0 + qs + quad * 4 + 0) * 2048 + col] = f2bf(oacc[nt][0] * inv0);
                out[(size_t)(q0 + qs + quad * 4 + 1) * 2048 + col] = f2bf(oacc[nt][1] * inv1);
                out[(size_t)(q0 + qs + quad * 4 + 2) * 2048 + col] = f2bf(oacc[nt][2] * inv2);
                out[(size_t)(q0 + qs + quad * 4 + 3) * 2048 + col] = f2bf(oacc[nt][3] * inv3);
            }
        }
        __syncthreads();
    }
}

// ---------------- silu(g)*u, bf16, in place into g ----------------
__global__ __launch_bounds__(256) void silu_mul_kernel(
    unsigned short* __restrict__ g, const unsigned short* __restrict__ u, int n8)
{
    int i = blockIdx.x * 256 + threadIdx.x;
    if (i >= n8) return;
    int4 gv = ((const int4*)g)[i];
    int4 uv = ((const int4*)u)[i];
    const unsigned short* gs = (const unsigned short*)&gv;
    const unsigned short* us = (const unsigned short*)&uv;
    __align__(16) unsigned short ov[8];
    #pragma unroll
    for (int j = 0; j < 8; ++j) {
        float gf = bf2f(gs[j]), uf = bf2f(us[j]);
        ov[j] = f2bf(gf * uf / (1.f + __expf(-gf)));
    }
    ((int4*)g)[i] = *(int4*)ov;
}

extern "C" void kernel_launch(void* const* d_in, const int* in_sizes, int n_in,
                              void* d_out, int out_size, void* d_ws, size_t ws_size,
                              hipStream_t stream)
{
    (void)in_sizes; (void)n_in; (void)out_size; (void)ws_size;
    const float* hidden  = (const float*)d_in[0];
    const float* sinb    = (const float*)d_in[1];
    const float* cosb    = (const float*)d_in[2];
    const float* wq_a    = (const float*)d_in[3];
    const float* q_a_ln  = (const float*)d_in[4];
    const float* wq_b    = (const float*)d_in[5];
    const float* wkv_a   = (const float*)d_in[6];
    const float* kv_a_ln = (const float*)d_in[7];
    const float* wkv_b   = (const float*)d_in[8];
    const float* wo      = (const float*)d_in[9];
    const float* in_ln   = (const float*)d_in[10];
    const float* post_ln = (const float*)d_in[11];
    const float* w_gate  = (const float*)d_in[12];
    const float* w_up    = (const float*)d_in[13];
    const float* w_down  = (const float*)d_in[14];
    const int*   pos     = (const int*)d_in[15];

    char* wsb = (char*)d_ws;
    size_t used = 0;
    auto alloc = [&](size_t bytes) {
        char* p = wsb + used;
        used += (bytes + 255) & ~(size_t)255;
        return p;
    };
    float* q_a   = (float*)alloc((size_t)2048 * 1536 * 4);
    float* ckv   = (float*)alloc((size_t)2048 * 576 * 4);
    float* h2    = (float*)alloc((size_t)2048 * 2048 * 4);
    unsigned short* xnb  = (unsigned short*)alloc((size_t)2048 * 2048 * 2);
    unsigned short* qab  = (unsigned short*)alloc((size_t)2048 * 1536 * 2);
    unsigned short* kvnb = (unsigned short*)alloc((size_t)2048 * 512 * 2);
    unsigned short* qbb  = (unsigned short*)alloc((size_t)2048 * 3072 * 2);
    unsigned short* kvbb = (unsigned short*)alloc((size_t)2048 * 4096 * 2);
    unsigned short* kpe  = (unsigned short*)alloc((size_t)2048 * 64 * 2);
    unsigned short* vtg  = (unsigned short*)alloc((size_t)16 * 128 * 2048 * 2);
    unsigned short* attb = (unsigned short*)alloc((size_t)2048 * 2048 * 2);
    unsigned short* gb   = (unsigned short*)alloc((size_t)2048 * 8192 * 2);
    unsigned short* ub   = (unsigned short*)alloc((size_t)2048 * 8192 * 2);
    unsigned short* wt   = (unsigned short*)alloc((size_t)16777216 * 2);
    float* outp = (float*)d_out;

    // zero split-K accumulation targets (atomicAdd destinations)
    hipMemsetAsync(q_a, 0, (size_t)2048 * 1536 * 4, stream);
    hipMemsetAsync(ckv, 0, (size_t)2048 * 576 * 4, stream);
    hipMemsetAsync(h2, 0, (size_t)2048 * 2048 * 4, stream);
    hipMemsetAsync(outp, 0, (size_t)2048 * 2048 * 4, stream);

    // x = rms(hidden) -> bf16
    rms_kernel<<<2048, 256, 0, stream>>>(hidden, 2048, in_ln, xnb, 2048, 2048);
    // q_a = x @ wq_a (fp32 out for rms) — 128-tile, split-K=2
    cast_transpose_kernel<<<dim3(24, 32), 256, 0, stream>>>(wq_a, wt, 2048, 1536);
    gemm_bf16_kernel<<<dim3(12, 16, 2), 256, 0, stream>>>(xnb, wt, q_a, nullptr, nullptr, 1536, 2048);
    rms_kernel<<<2048, 256, 0, stream>>>(q_a, 1536, q_a_ln, qab, 1536, 1536);
    // q = q_a @ wq_b -> bf16 — 128-tile
    cast_transpose_kernel<<<dim3(48, 24), 256, 0, stream>>>(wq_b, wt, 1536, 3072);
    gemm_bf16_kernel<<<dim3(24, 16), 256, 0, stream>>>(qab, wt, nullptr, qbb, nullptr, 3072, 1536);
    // ckv = x @ wkv_a (fp32, N=576) — 128-tile, split-K=4
    cast_transpose_kernel<<<dim3(10, 32), 256, 0, stream>>>(wkv_a, wt, 2048, 576);
    gemm_bf16_kernel<<<dim3(5, 16, 4), 256, 0, stream>>>(xnb, wt, ckv, nullptr, nullptr, 576, 2048);
    // kvn = rms(ckv[:, :512]) -> bf16
    rms_kernel<<<2048, 256, 0, stream>>>(ckv, 576, kv_a_ln, kvnb, 512, 512);
    // kv = kvn @ wkv_b -> bf16 — 128-tile
    cast_transpose_kernel<<<dim3(64, 8), 256, 0, stream>>>(wkv_b, wt, 512, 4096);
    gemm_bf16_kernel<<<dim3(32, 16), 256, 0, stream>>>(kvnb, wt, nullptr, kvbb, nullptr, 4096, 512);
    // RoPE
    rope_q_kernel<<<4096, 256, 0, stream>>>(qbb, cosb, sinb, pos);
    rope_kpe_kernel<<<256, 256, 0, stream>>>(ckv, kpe, cosb, sinb, pos);
    // V transpose
    vtrans_kernel<<<dim3(32, 2, 16), 256, 0, stream>>>(kvbb, vtg);
    // attention -> bf16
    attn_mfma_kernel<<<dim3(16, 16), 512, 0, stream>>>(qbb, kvbb, kpe, vtg, attb);
    // h2 = att @ wo + hidden (fp32) — 256-tile 4-phase, split-K=4 (256 blocks)
    cast_transpose_kernel<<<dim3(32, 32), 256, 0, stream>>>(wo, wt, 2048, 2048);
    gemm256_kernel<<<dim3(8, 8, 4), 512, 0, stream>>>(attb, wt, h2, nullptr, hidden, 2048, 2048);
    // y = rms(h2) -> bf16
    rms_kernel<<<2048, 256, 0, stream>>>(h2, 2048, post_ln, xnb, 2048, 2048);
    // gate, up -> bf16 — 256-tile 4-phase (256 blocks each)
    cast_transpose_kernel<<<dim3(128, 32), 256, 0, stream>>>(w_gate, wt, 2048, 8192);
    gemm256_kernel<<<dim3(32, 8, 1), 512, 0, stream>>>(xnb, wt, nullptr, gb, nullptr, 8192, 2048);
    cast_transpose_kernel<<<dim3(128, 32), 256, 0, stream>>>(w_up, wt, 2048, 8192);
    gemm256_kernel<<<dim3(32, 8, 1), 512, 0, stream>>>(xnb, wt, nullptr, ub, nullptr, 8192, 2048);
    // gb = silu(gb)*ub
    silu_mul_kernel<<<8192, 256, 0, stream>>>(gb, ub, 2097152);
    // out = gb @ w_down + h2 — 256-tile 4-phase, split-K=4 (256 blocks)
    cast_transpose_kernel<<<dim3(32, 128), 256, 0, stream>>>(w_down, wt, 8192, 2048);
    gemm256_kernel<<<dim3(8, 8, 4), 512, 0, stream>>>(gb, wt, outp, nullptr, h2, 2048, 8192);
}

// Round 5
// 923.842 us; speedup vs baseline: 1.1582x; 1.1582x over previous
//
#include <hip/hip_runtime.h>
#include <math.h>

#define ATTN_SCALE 0.07216878364870322f  // 192^-0.5

typedef __attribute__((ext_vector_type(8))) short short8;
typedef __attribute__((ext_vector_type(4))) float floatx4;

__device__ __forceinline__ unsigned short f2bf(float f) {
    union { float f; unsigned int u; } v; v.f = f;
    unsigned int r = v.u + 0x7fffu + ((v.u >> 16) & 1u);
    return (unsigned short)(r >> 16);
}
__device__ __forceinline__ float bf2f(unsigned short h) {
    union { unsigned int u; float f; } v; v.u = ((unsigned int)h) << 16;
    return v.f;
}
__device__ __forceinline__ void gld16(const void* g, void* l) {
    __builtin_amdgcn_global_load_lds(
        (const __attribute__((address_space(1))) unsigned int*)g,
        (__attribute__((address_space(3))) unsigned int*)l, 16, 0, 0);
}

// ---------------- RMSNorm fp32 in -> bf16 out ----------------
__global__ __launch_bounds__(256) void rms_kernel(
    const float* __restrict__ in, int ld_in,
    const float* __restrict__ w,
    unsigned short* __restrict__ out, int ld_out, int N)
{
    const int row = blockIdx.x;
    const int tid = threadIdx.x;
    const float* x = in + (size_t)row * ld_in;
    float ss = 0.f;
    for (int i = tid * 4; i < N; i += 1024) {
        float4 v = *(const float4*)(x + i);
        ss += v.x * v.x + v.y * v.y + v.z * v.z + v.w * v.w;
    }
    #pragma unroll
    for (int off = 32; off > 0; off >>= 1)
        ss += __shfl_down(ss, off);
    __shared__ float red[4];
    const int lane = tid & 63, wid = tid >> 6;
    if (lane == 0) red[wid] = ss;
    __syncthreads();
    const float tot = red[0] + red[1] + red[2] + red[3];
    const float rs = rsqrtf(tot / (float)N + 1e-6f);
    unsigned short* o = out + (size_t)row * ld_out;
    for (int i = tid * 4; i < N; i += 1024) {
        float4 v = *(const float4*)(x + i);
        float4 wv = *(const float4*)(w + i);
        __align__(8) unsigned short ov[4];
        ov[0] = f2bf(v.x * rs * wv.x);
        ov[1] = f2bf(v.y * rs * wv.y);
        ov[2] = f2bf(v.z * rs * wv.z);
        ov[3] = f2bf(v.w * rs * wv.w);
        *(uint2*)&o[i] = *(uint2*)ov;
    }
}

// ---------------- weight cast+transpose: W fp32[K,N] -> Wt bf16[Npad,K] ----------------
__global__ __launch_bounds__(256) void cast_transpose_kernel(
    const float* __restrict__ W, unsigned short* __restrict__ Wt,
    int K, int N)
{
    __shared__ float tile[64][65];
    const int tid = threadIdx.x;
    const int kb = blockIdx.y * 64;
    const int nb = blockIdx.x * 64;
    const int r  = tid >> 2;
    const int c0 = (tid & 3) * 16;
    if (nb + 64 <= N) {
        #pragma unroll
        for (int j = 0; j < 16; j += 4)
            *(float4*)&tile[r][c0 + j] =
                *(const float4*)&W[(size_t)(kb + r) * N + nb + c0 + j];
    } else {
        for (int j = 0; j < 16; ++j) {
            int n = nb + c0 + j;
            tile[r][c0 + j] = (n < N) ? W[(size_t)(kb + r) * N + n] : 0.f;
        }
    }
    __syncthreads();
    __align__(16) unsigned short ov[16];
    #pragma unroll
    for (int j = 0; j < 16; ++j) ov[j] = f2bf(tile[c0 + j][r]);
    int4* dst = (int4*)&Wt[(size_t)(nb + r) * K + kb + c0];
    dst[0] = ((int4*)ov)[0];
    dst[1] = ((int4*)ov)[1];
}

// ---------------- split-K partial reduce: out = p0+p1[+p2+p3][+R], float4 ----------------
__global__ __launch_bounds__(256) void reduce_kernel(
    const float* __restrict__ p0, const float* __restrict__ p1,
    const float* __restrict__ p2, const float* __restrict__ p3,
    const float* __restrict__ R, float* __restrict__ out, int n4)
{
    int i = blockIdx.x * 256 + threadIdx.x;
    if (i >= n4) return;
    float4 a = ((const float4*)p0)[i];
    float4 b = ((const float4*)p1)[i];
    float4 s;
    s.x = a.x + b.x; s.y = a.y + b.y; s.z = a.z + b.z; s.w = a.w + b.w;
    if (p2) {
        float4 c = ((const float4*)p2)[i];
        float4 d = ((const float4*)p3)[i];
        s.x += c.x + d.x; s.y += c.y + d.y; s.z += c.z + d.z; s.w += c.w + d.w;
    }
    if (R) {
        float4 r = ((const float4*)R)[i];
        s.x += r.x; s.y += r.y; s.z += r.z; s.w += r.w;
    }
    ((float4*)out)[i] = s;
}

// ---------------- bf16 MFMA GEMM 128-tile (kept for small shapes) ----------------
// gridDim.z>1: P01/P23 are split-K partial buffers (plain stores, no atomics);
// slice kz stores to P01+kz*MN (kz<2) or P23+(kz-2)*MN.
__global__ __launch_bounds__(256) void gemm_bf16_kernel(
    const unsigned short* __restrict__ A,   // [M,K] bf16
    const unsigned short* __restrict__ Bt,  // [Npad,K] bf16
    float* __restrict__ C,                  // fp32 out (or null)
    unsigned short* __restrict__ Cb,        // bf16 out (or null)
    const float* __restrict__ R,            // fp32 residual (or null)
    float* __restrict__ P01,                // split-K partials z0/z1 (or null)
    float* __restrict__ P23,                // split-K partials z2/z3 (or null)
    int N, int K)
{
    __shared__ __align__(16) unsigned short As[2][4096];
    __shared__ __align__(16) unsigned short Bs[2][4096];
    const int tid = threadIdx.x;
    const int w  = tid >> 6;
    const int l  = tid & 63;
    const int lm = l & 15;
    const int lk = l >> 4;
    const int row0 = blockIdx.y * 128;
    const int col0 = blockIdx.x * 128;
    const int wm = (w >> 1) * 64;
    const int wn = (w & 1) * 64;
    const int nsplit = gridDim.z;
    const int kz = blockIdx.z;
    const int kchunk = K / nsplit;
    const int kbase = kz * kchunk;

    const unsigned short* a0 = A  + (size_t)(row0 + w * 16 + lm) * K + kbase + lk * 8;
    const unsigned short* a1 = a0 + (size_t)64 * K;
    const unsigned short* b0 = Bt + (size_t)(col0 + w * 16 + lm) * K + kbase + lk * 8;
    const unsigned short* b1 = b0 + (size_t)64 * K;
    const int s0 = w * 512 + l * 8;
    const int s1 = (w + 4) * 512 + l * 8;

    floatx4 acc[4][4];
    #pragma unroll
    for (int i = 0; i < 4; ++i)
        #pragma unroll
        for (int j = 0; j < 4; ++j)
            acc[i][j] = (floatx4){0.f, 0.f, 0.f, 0.f};

    gld16(a0, &As[0][s0]);
    gld16(a1, &As[0][s1]);
    gld16(b0, &Bs[0][s0]);
    gld16(b1, &Bs[0][s1]);
    a0 += 32; a1 += 32; b0 += 32; b1 += 32;
    __syncthreads();

    const int niter = kchunk >> 5;
    int cur = 0;
    for (int t = 0; t < niter; ++t) {
        if (t + 1 < niter) {
            gld16(a0, &As[cur ^ 1][s0]);
            gld16(a1, &As[cur ^ 1][s1]);
            gld16(b0, &Bs[cur ^ 1][s0]);
            gld16(b1, &Bs[cur ^ 1][s1]);
            a0 += 32; a1 += 32; b0 += 32; b1 += 32;
        }
        short8 af[4], bg_[4];
        #pragma unroll
        for (int i = 0; i < 4; ++i)
            af[i] = *(const short8*)&As[cur][((w >> 1) * 4 + i) * 512 + l * 8];
        #pragma unroll
        for (int j = 0; j < 4; ++j)
            bg_[j] = *(const short8*)&Bs[cur][((w & 1) * 4 + j) * 512 + l * 8];
        #pragma unroll
        for (int i = 0; i < 4; ++i)
            #pragma unroll
            for (int j = 0; j < 4; ++j)
                acc[i][j] = __builtin_amdgcn_mfma_f32_16x16x32_bf16(
                    af[i], bg_[j], acc[i][j], 0, 0, 0);
        __syncthreads();
        cur ^= 1;
    }

    const int quad = l >> 4;
    const bool ng = (col0 + 128 > N);
    float* P = nullptr;
    if (P01) {
        const size_t MN = (size_t)gridDim.y * 128 * N;
        P = (kz < 2) ? (P01 + (size_t)kz * MN) : (P23 + (size_t)(kz - 2) * MN);
    }
    #pragma unroll
    for (int i = 0; i < 4; ++i) {
        #pragma unroll
        for (int r = 0; r < 4; ++r) {
            const int m = row0 + wm + i * 16 + quad * 4 + r;
            #pragma unroll
            for (int j = 0; j < 4; ++j) {
                const int n = col0 + wn + j * 16 + lm;
                if (ng && n >= N) continue;
                const size_t off = (size_t)m * N + n;
                float v = acc[i][j][r];
                if (P) {
                    P[off] = v;
                } else if (Cb) {
                    Cb[off] = f2bf(v);
                } else {
                    if (R) v += R[off];
                    C[off] = v;
                }
            }
        }
    }
}

// ---------------- bf16 MFMA GEMM 256-tile, 4-phase fine interleave per K-tile ----------------
// Split-K mode writes plain fp32 partials (no atomics); reduce_kernel sums them.
__global__ __launch_bounds__(512) void gemm256_kernel(
    const unsigned short* __restrict__ A,   // [M,K] bf16
    const unsigned short* __restrict__ Bt,  // [N,K] bf16
    float* __restrict__ C,                  // fp32 out (or null)
    unsigned short* __restrict__ Cb,        // bf16 out (or null)
    const float* __restrict__ R,            // fp32 residual (or null)
    float* __restrict__ P01,                // split-K partials z0/z1 (or null)
    float* __restrict__ P23,                // split-K partials z2/z3 (or null)
    int N, int K)
{
    __shared__ __align__(16) unsigned short As[2][16384];  // 2 x 32 KB
    __shared__ __align__(16) unsigned short Bs[2][16384];  // 2 x 32 KB
    const int tid = threadIdx.x;
    const int w   = tid >> 6;
    const int l   = tid & 63;
    const int lm  = l & 15;
    const int quad = l >> 4;
    const int wm2 = w >> 2;   // 0..1
    const int wn4 = w & 3;    // 0..3

    // XCD-aware bijective swizzle of flat (y,x) id (T1, m204 variant)
    const int gx = gridDim.x;
    const int nwg = gx * gridDim.y;
    int bid = blockIdx.y * gx + blockIdx.x;
    {
        const int q = nwg >> 3, r = nwg & 7;
        const int xcd = bid & 7, off = bid >> 3;
        bid = (xcd < r ? xcd * (q + 1) : r * (q + 1) + (xcd - r) * q) + off;
    }
    const int row0 = (bid / gx) * 256;
    const int col0 = (bid % gx) * 256;

    const int nsplit = gridDim.z;
    const int kz = blockIdx.z;
    const int kchunk = K / nsplit;
    const int kbase = kz * kchunk;

    const int slk = (tid >> 4) & 7;     // k-subchunk 0..7
    const int srg = tid >> 7;           // row-subgroup 0..3
    const unsigned short* sa = A  + (size_t)(row0 + srg * 16 + lm) * K + kbase + slk * 8;
    const unsigned short* sb = Bt + (size_t)(col0 + srg * 16 + lm) * K + kbase + slk * 8;

    floatx4 acc[8][4];
    #pragma unroll
    for (int i = 0; i < 8; ++i)
        #pragma unroll
        for (int j = 0; j < 4; ++j)
            acc[i][j] = (floatx4){0.f, 0.f, 0.f, 0.f};

    const int nt = kchunk >> 6;
    #pragma unroll
    for (int j = 0; j < 4; ++j) {
        gld16(sa + (size_t)j * 64 * K, (char*)As[0] + j * 8192 + tid * 16);
        gld16(sb + (size_t)j * 64 * K, (char*)Bs[0] + j * 8192 + tid * 16);
    }
    asm volatile("s_waitcnt vmcnt(0)" ::: "memory");
    __builtin_amdgcn_sched_barrier(0);
    __builtin_amdgcn_s_barrier();
    __builtin_amdgcn_sched_barrier(0);

    for (int t = 0; t < nt; ++t) {
        const int p = t & 1;
        const char* ab = (const char*)As[p] + wm2 * 16384 + l * 16;
        const char* bb = (const char*)Bs[p] + wn4 * 8192  + l * 16;
        char* dA = (char*)As[p ^ 1] + tid * 16;
        char* dB = (char*)Bs[p ^ 1] + tid * 16;
        const size_t ko = (size_t)(t + 1) * 64;
        const bool pre = (t + 1 < nt);
        short8 bfr[4][2];
        short8 afr[2][2];

        #pragma unroll
        for (int q = 0; q < 4; ++q) {
            if (q == 0) {
                #pragma unroll
                for (int j = 0; j < 4; ++j) {
                    bfr[j][0] = *(const short8*)(bb + j * 2048);
                    bfr[j][1] = *(const short8*)(bb + j * 2048 + 1024);
                }
            }
            afr[0][0] = *(const short8*)(ab + (2 * q) * 2048);
            afr[0][1] = *(const short8*)(ab + (2 * q) * 2048 + 1024);
            afr[1][0] = *(const short8*)(ab + (2 * q + 1) * 2048);
            afr[1][1] = *(const short8*)(ab + (2 * q + 1) * 2048 + 1024);
            if (pre) {
                if (q == 0) {
                    gld16(sa + ko, dA);
                    gld16(sb + ko, dB);
                    gld16(sa + (size_t)64 * K + ko, dA + 8192);
                    gld16(sb + (size_t)64 * K + ko, dB + 8192);
                } else if (q == 1) {
                    gld16(sa + (size_t)128 * K + ko, dA + 16384);
                    gld16(sb + (size_t)128 * K + ko, dB + 16384);
                    gld16(sa + (size_t)192 * K + ko, dA + 24576);
                    gld16(sb + (size_t)192 * K + ko, dB + 24576);
                }
            }
            __builtin_amdgcn_sched_barrier(0);
            __builtin_amdgcn_s_barrier();
            __builtin_amdgcn_sched_barrier(0);
            __builtin_amdgcn_s_setprio(1);
            #pragma unroll
            for (int c = 0; c < 2; ++c)
                #pragma unroll
                for (int i2 = 0; i2 < 2; ++i2)
                    #pragma unroll
                    for (int j = 0; j < 4; ++j)
                        acc[2 * q + i2][j] = __builtin_amdgcn_mfma_f32_16x16x32_bf16(
                            afr[i2][c], bfr[j][c], acc[2 * q + i2][j], 0, 0, 0);
            __builtin_amdgcn_s_setprio(0);
            __builtin_amdgcn_sched_barrier(0);
            if (q == 3)
                asm volatile("s_waitcnt vmcnt(0)" ::: "memory");  // tile t+1 landed
            __builtin_amdgcn_s_barrier();
            __builtin_amdgcn_sched_barrier(0);
        }
    }

    float* P = nullptr;
    if (P01) {
        const size_t MN = (size_t)gridDim.y * 256 * N;
        P = (kz < 2) ? (P01 + (size_t)kz * MN) : (P23 + (size_t)(kz - 2) * MN);
    }
    #pragma unroll
    for (int i = 0; i < 8; ++i) {
        #pragma unroll
        for (int r = 0; r < 4; ++r) {
            const int m = row0 + wm2 * 128 + i * 16 + quad * 4 + r;
            #pragma unroll
            for (int j = 0; j < 4; ++j) {
                const int n = col0 + wn4 * 64 + j * 16 + lm;
                const size_t off = (size_t)m * N + n;
                float v = acc[i][j][r];
                if (P) {
                    P[off] = v;
                } else if (Cb) {
                    Cb[off] = f2bf(v);
                } else {
                    if (R) v += R[off];
                    C[off] = v;
                }
            }
        }
    }
}

// ---------------- RoPE on bf16 q (in place, interleave -> half) ----------------
__global__ __launch_bounds__(256) void rope_q_kernel(
    unsigned short* __restrict__ x,
    const float* __restrict__ cosb, const float* __restrict__ sinb,
    const int* __restrict__ pos_ids)
{
    const int gid = blockIdx.x * 256 + threadIdx.x;
    const int i = gid & 31;
    const int grp = gid >> 5;
    const int hh = grp & 15;
    const int row = grp >> 4;
    unsigned short* base = x + (size_t)row * 3072 + hh * 192 + 128;
    const float x0 = bf2f(base[2 * i]);
    const float x1 = bf2f(base[2 * i + 1]);
    const int p = pos_ids[row];
    const float c = cosb[p * 64 + i];
    const float s = sinb[p * 64 + i];
    __syncthreads();
    base[i]      = f2bf(x0 * c - x1 * s);
    base[32 + i] = f2bf(x1 * c + x0 * s);
}

// ---------------- RoPE k_pe: ckv fp32 cols 512.. -> kpe bf16 [2048][64] ----------------
__global__ __launch_bounds__(256) void rope_kpe_kernel(
    const float* __restrict__ ckv, unsigned short* __restrict__ kpe,
    const float* __restrict__ cosb, const float* __restrict__ sinb,
    const int* __restrict__ pos_ids)
{
    const int gid = blockIdx.x * 256 + threadIdx.x;
    const int i = gid & 31;
    const int row = gid >> 5;
    const float x0 = ckv[(size_t)row * 576 + 512 + 2 * i];
    const float x1 = ckv[(size_t)row * 576 + 512 + 2 * i + 1];
    const int p = pos_ids[row];
    const float c = cosb[p * 64 + i];
    const float s = sinb[p * 64 + i];
    kpe[(size_t)row * 64 + i]      = f2bf(x0 * c - x1 * s);
    kpe[(size_t)row * 64 + 32 + i] = f2bf(x1 * c + x0 * s);
}

// ---------------- V transpose: kvb bf16 -> vtg[16][128][2048] bf16 ----------------
__global__ __launch_bounds__(256) void vtrans_kernel(
    const unsigned short* __restrict__ kvb, unsigned short* __restrict__ vtg)
{
    __shared__ unsigned short tile[64][72];
    const int tid = threadIdx.x;
    const int s0 = blockIdx.x * 64;
    const int d0 = blockIdx.y * 64;
    const int h  = blockIdx.z;
    const int r  = tid >> 2;
    const int c0 = (tid & 3) * 16;
    *(int4*)&tile[r][c0] =
        *(const int4*)&kvb[(size_t)(s0 + r) * 4096 + h * 256 + 128 + d0 + c0];
    *(int4*)&tile[r][c0 + 8] =
        *(const int4*)&kvb[(size_t)(s0 + r) * 4096 + h * 256 + 128 + d0 + c0 + 8];
    __syncthreads();
    __align__(16) unsigned short ov[16];
    #pragma unroll
    for (int j = 0; j < 16; ++j) ov[j] = tile[c0 + j][r];
    unsigned short* dst = vtg + ((size_t)(h * 128 + d0 + r)) * 2048 + s0 + c0;
    ((int4*)dst)[0] = ((int4*)ov)[0];
    ((int4*)dst)[1] = ((int4*)ov)[1];
}

// ---------------- MFMA flash attention ----------------
__global__ __launch_bounds__(512) void attn_mfma_kernel(
    const unsigned short* __restrict__ qb,   // [2048][3072] bf16 (roped)
    const unsigned short* __restrict__ kvb,  // [2048][4096] bf16
    const unsigned short* __restrict__ kpe,  // [2048][64] bf16 (roped)
    const unsigned short* __restrict__ vtg,  // [16][128][2048] bf16
    unsigned short* __restrict__ out)        // [2048][2048] bf16
{
    __shared__ __align__(16) unsigned short Kf[128 * 200];   // 51200 B, row stride 400 B
    __shared__ __align__(16) unsigned short Vt[2][128 * 136];// 2x34816 B, row stride 272 B
    __shared__ __align__(16) unsigned short Ps[64 * 136];    // 17408 B
    __shared__ float pmax_s[8][64];
    __shared__ float psum_s[8][64];
    __shared__ __align__(16) float m_state[64];
    __shared__ __align__(16) float l_state[64];
    __shared__ __align__(16) float alpha_s[64];
    __shared__ __align__(16) float mnew_s[64];

    const int tid  = threadIdx.x;
    const int w    = tid >> 6;
    const int l    = tid & 63;
    const int l15  = l & 15;
    const int quad = l >> 4;
    const int h    = blockIdx.y;
    const int qs   = (w & 3) * 16;   // PV q strip
    const int dh   = (w >> 2) * 64;  // PV d half

    for (int pass = 0; pass < 2; ++pass) {
        const int qt = pass ? (31 - (int)blockIdx.x) : (int)blockIdx.x;
        const int q0 = qt * 64;
        const int ntiles = (qt >> 1) + 1;

        short8 qf[4][6];
        #pragma unroll
        for (int nt = 0; nt < 4; ++nt)
            #pragma unroll
            for (int c = 0; c < 6; ++c)
                qf[nt][c] = *(const short8*)&qb[(size_t)(q0 + nt * 16 + l15) * 3072
                                               + h * 192 + c * 32 + quad * 8];

        floatx4 oacc[4];
        #pragma unroll
        for (int nt = 0; nt < 4; ++nt) oacc[nt] = (floatx4){0.f, 0.f, 0.f, 0.f};
        if (tid < 64) { m_state[tid] = -3e38f; l_state[tid] = 0.f; }

        // stage tile 0
        {
            const int k0 = 0;
            for (int s = w; s < 50; s += 8) {
                unsigned ab = s * 1024 + l * 16;
                unsigned row = ab / 400u;
                unsigned g = (ab - row * 400u) >> 4;
                const unsigned short* src;
                if (g < 16u)      src = kvb + (size_t)(k0 + row) * 4096 + h * 256 + g * 8;
                else if (g < 24u) src = kpe + (size_t)(k0 + row) * 64 + (g - 16u) * 8;
                else              src = kpe + (size_t)(k0 + row) * 64;
                gld16(src, (char*)Kf + ab);
            }
            for (int s = w; s < 34; s += 8) {
                unsigned ab = s * 1024 + l * 16;
                unsigned row = ab / 272u;
                unsigned g = (ab - row * 272u) >> 4;
                const unsigned short* src =
                    vtg + (size_t)(h * 128 + row) * 2048 + k0 + (g < 16u ? g * 8 : 0u);
                gld16(src, (char*)Vt[0] + ab);
            }
        }

        for (int kt = 0; kt < ntiles; ++kt) {
            const int k0 = kt * 128;
            const int vb = kt & 1;
            __syncthreads();  // staging of kt complete; prev-iter LDS reads done

            // ---- QK^T ----
            floatx4 st[4];
            #pragma unroll
            for (int nt = 0; nt < 4; ++nt) st[nt] = (floatx4){0.f, 0.f, 0.f, 0.f};
            #pragma unroll
            for (int c = 0; c < 6; ++c) {
                short8 kf = *(const short8*)&Kf[(w * 16 + l15) * 200 + c * 32 + quad * 8];
                #pragma unroll
                for (int nt = 0; nt < 4; ++nt)
                    st[nt] = __builtin_amdgcn_mfma_f32_16x16x32_bf16(kf, qf[nt][c], st[nt], 0, 0, 0);
            }
            #pragma unroll
            for (int nt = 0; nt < 4; ++nt) {
                const int qq = q0 + nt * 16 + l15;
                float vmax = -3e38f;
                #pragma unroll
                for (int r = 0; r < 4; ++r) {
                    const int kpos = k0 + w * 16 + quad * 4 + r;
                    float v = st[nt][r] * ATTN_SCALE;
                    if (kpos > qq) v = -3e38f;
                    st[nt][r] = v;
                    vmax = fmaxf(vmax, v);
                }
                vmax = fmaxf(vmax, __shfl_xor(vmax, 16));
                vmax = fmaxf(vmax, __shfl_xor(vmax, 32));
                if (quad == 0) pmax_s[w][nt * 16 + l15] = vmax;
            }
            __syncthreads();
            if (tid < 64) {
                float mp = m_state[tid];
                float mn = mp;
                #pragma unroll
                for (int ww = 0; ww < 8; ++ww) mn = fmaxf(mn, pmax_s[ww][tid]);
                alpha_s[tid] = __expf(mp - mn);
                mnew_s[tid] = mn;
                m_state[tid] = mn;
            }
            __syncthreads();

            // ---- p = exp(s - m), pack -> Ps, col sums ----
            #pragma unroll
            for (int nt = 0; nt < 4; ++nt) {
                const float mn = mnew_s[nt * 16 + l15];
                float vsum = 0.f;
                __align__(8) unsigned short pb[4];
                #pragma unroll
                for (int r = 0; r < 4; ++r) {
                    float p = __expf(st[nt][r] - mn);
                    vsum += p;
                    pb[r] = f2bf(p);
                }
                *(uint2*)&Ps[(nt * 16 + l15) * 136 + w * 16 + quad * 4] = *(uint2*)pb;
                vsum += __shfl_xor(vsum, 16);
                vsum += __shfl_xor(vsum, 32);
                if (quad == 0) psum_s[w][nt * 16 + l15] = vsum;
            }
            {
                float4 al4 = *(const float4*)&alpha_s[qs + quad * 4];
                #pragma unroll
                for (int nt = 0; nt < 4; ++nt) {
                    oacc[nt][0] *= al4.x; oacc[nt][1] *= al4.y;
                    oacc[nt][2] *= al4.z; oacc[nt][3] *= al4.w;
                }
            }
            __syncthreads();
            if (tid < 64) {
                float acc = 0.f;
                #pragma unroll
                for (int ww = 0; ww < 8; ++ww) acc += psum_s[ww][tid];
                l_state[tid] = l_state[tid] * alpha_s[tid] + acc;
            }
            if (kt + 1 < ntiles) {
                const int k1 = k0 + 128;
                for (int s = w; s < 50; s += 8) {
                    unsigned ab = s * 1024 + l * 16;
                    unsigned row = ab / 400u;
                    unsigned g = (ab - row * 400u) >> 4;
                    const unsigned short* src;
                    if (g < 16u)      src = kvb + (size_t)(k1 + row) * 4096 + h * 256 + g * 8;
                    else if (g < 24u) src = kpe + (size_t)(k1 + row) * 64 + (g - 16u) * 8;
                    else              src = kpe + (size_t)(k1 + row) * 64;
                    gld16(src, (char*)Kf + ab);
                }
                for (int s = w; s < 34; s += 8) {
                    unsigned ab = s * 1024 + l * 16;
                    unsigned row = ab / 272u;
                    unsigned g = (ab - row * 272u) >> 4;
                    const unsigned short* src =
                        vtg + (size_t)(h * 128 + row) * 2048 + k1 + (g < 16u ? g * 8 : 0u);
                    gld16(src, (char*)Vt[vb ^ 1] + ab);
                }
            }
            // ---- PV ----
            #pragma unroll
            for (int c = 0; c < 4; ++c) {
                short8 pf = *(const short8*)&Ps[(qs + l15) * 136 + c * 32 + quad * 8];
                #pragma unroll
                for (int nt = 0; nt < 4; ++nt) {
                    short8 vf = *(const short8*)&Vt[vb][(dh + nt * 16 + l15) * 136
                                                       + c * 32 + quad * 8];
                    oacc[nt] = __builtin_amdgcn_mfma_f32_16x16x32_bf16(pf, vf, oacc[nt], 0, 0, 0);
                }
            }
        }
        __syncthreads();

        // ---- epilogue ----
        {
            float4 l4 = *(const float4*)&l_state[qs + quad * 4];
            float inv0 = 1.f / l4.x, inv1 = 1.f / l4.y, inv2 = 1.f / l4.z, inv3 = 1.f / l4.w;
            #pragma unroll
            for (int nt = 0; nt < 4; ++nt) {
                const size_t col = h * 128 + dh + nt * 16 + l15;
                out[(size_t)(q0 + qs + quad * 4 + 0) * 2048 + col] = f2bf(oacc[nt][0] * inv0);
                out[(size_t)(q0 + qs + quad * 4 + 1) * 2048 + col] = f2bf(oacc[nt][1] * inv1);
                out[(size_t)(q0 + qs + quad * 4 + 2) * 2048 + col] = f2bf(oacc[nt][2] * inv2);
                out[(size_t)(q0 + qs + quad * 4 + 3) * 2048 + col] = f2bf(oacc[nt][3] * inv3);
            }
        }
        __syncthreads();
    }
}

// ---------------- silu(g)*u, bf16, in place into g ----------------
__global__ __launch_bounds__(256) void silu_mul_kernel(
    unsigned short* __restrict__ g, const unsigned short* __restrict__ u, int n8)
{
    int i = blockIdx.x * 256 + threadIdx.x;
    if (i >= n8) return;
    int4 gv = ((const int4*)g)[i];
    int4 uv = ((const int4*)u)[i];
    const unsigned short* gs = (const unsigned short*)&gv;
    const unsigned short* us = (const unsigned short*)&uv;
    __align__(16) unsigned short ov[8];
    #pragma unroll
    for (int j = 0; j < 8; ++j) {
        float gf = bf2f(gs[j]), uf = bf2f(us[j]);
        ov[j] = f2bf(gf * uf / (1.f + __expf(-gf)));
    }
    ((int4*)g)[i] = *(int4*)ov;
}

extern "C" void kernel_launch(void* const* d_in, const int* in_sizes, int n_in,
                              void* d_out, int out_size, void* d_ws, size_t ws_size,
                              hipStream_t stream)
{
    (void)in_sizes; (void)n_in; (void)out_size; (void)ws_size;
    const float* hidden  = (const float*)d_in[0];
    const float* sinb    = (const float*)d_in[1];
    const float* cosb    = (const float*)d_in[2];
    const float* wq_a    = (const float*)d_in[3];
    const float* q_a_ln  = (const float*)d_in[4];
    const float* wq_b    = (const float*)d_in[5];
    const float* wkv_a   = (const float*)d_in[6];
    const float* kv_a_ln = (const float*)d_in[7];
    const float* wkv_b   = (const float*)d_in[8];
    const float* wo      = (const float*)d_in[9];
    const float* in_ln   = (const float*)d_in[10];
    const float* post_ln = (const float*)d_in[11];
    const float* w_gate  = (const float*)d_in[12];
    const float* w_up    = (const float*)d_in[13];
    const float* w_down  = (const float*)d_in[14];
    const int*   pos     = (const int*)d_in[15];

    char* wsb = (char*)d_ws;
    size_t used = 0;
    auto alloc = [&](size_t bytes) {
        char* p = wsb + used;
        used += (bytes + 255) & ~(size_t)255;
        return p;
    };
    float* q_a   = (float*)alloc((size_t)2048 * 1536 * 4);
    float* ckv   = (float*)alloc((size_t)2048 * 576 * 4);
    float* h2    = (float*)alloc((size_t)2048 * 2048 * 4);
    unsigned short* xnb  = (unsigned short*)alloc((size_t)2048 * 2048 * 2);
    unsigned short* qab  = (unsigned short*)alloc((size_t)2048 * 1536 * 2);
    unsigned short* kvnb = (unsigned short*)alloc((size_t)2048 * 512 * 2);
    unsigned short* qbb  = (unsigned short*)alloc((size_t)2048 * 3072 * 2);
    unsigned short* kvbb = (unsigned short*)alloc((size_t)2048 * 4096 * 2);
    unsigned short* kpe  = (unsigned short*)alloc((size_t)2048 * 64 * 2);
    unsigned short* vtg  = (unsigned short*)alloc((size_t)16 * 128 * 2048 * 2);
    unsigned short* attb = (unsigned short*)alloc((size_t)2048 * 2048 * 2);
    unsigned short* gb   = (unsigned short*)alloc((size_t)2048 * 8192 * 2);
    unsigned short* ub   = (unsigned short*)alloc((size_t)2048 * 8192 * 2);
    unsigned short* wt   = (unsigned short*)alloc((size_t)16777216 * 2);
    float* outp = (float*)d_out;

    // x = rms(hidden) -> bf16
    rms_kernel<<<2048, 256, 0, stream>>>(hidden, 2048, in_ln, xnb, 2048, 2048);
    // q_a = x @ wq_a — 128-tile split-K=2, partials in gb (dead), reduce -> q_a
    cast_transpose_kernel<<<dim3(24, 32), 256, 0, stream>>>(wq_a, wt, 2048, 1536);
    {
        float* P = (float*)gb;  // 2 x 12.6 MB <= 33.5 MB
        gemm_bf16_kernel<<<dim3(12, 16, 2), 256, 0, stream>>>(
            xnb, wt, nullptr, nullptr, nullptr, P, P, 1536, 2048);
        reduce_kernel<<<3072, 256, 0, stream>>>(
            P, P + (size_t)2048 * 1536, nullptr, nullptr, nullptr, q_a, 786432);
    }
    rms_kernel<<<2048, 256, 0, stream>>>(q_a, 1536, q_a_ln, qab, 1536, 1536);
    // q = q_a @ wq_b -> bf16 — 128-tile
    cast_transpose_kernel<<<dim3(48, 24), 256, 0, stream>>>(wq_b, wt, 1536, 3072);
    gemm_bf16_kernel<<<dim3(24, 16), 256, 0, stream>>>(
        qab, wt, nullptr, qbb, nullptr, nullptr, nullptr, 3072, 1536);
    // ckv = x @ wkv_a (N=576) — 128-tile split-K=4, partials in ub (dead), reduce -> ckv
    cast_transpose_kernel<<<dim3(10, 32), 256, 0, stream>>>(wkv_a, wt, 2048, 576);
    {
        float* P = (float*)ub;  // 4 x 4.7 MB <= 33.5 MB
        const size_t MN = (size_t)2048 * 576;
        gemm_bf16_kernel<<<dim3(5, 16, 4), 256, 0, stream>>>(
            xnb, wt, nullptr, nullptr, nullptr, P, P + 2 * MN, 576, 2048);
        reduce_kernel<<<1152, 256, 0, stream>>>(
            P, P + MN, P + 2 * MN, P + 3 * MN, nullptr, ckv, 294912);
    }
    // kvn = rms(ckv[:, :512]) -> bf16
    rms_kernel<<<2048, 256, 0, stream>>>(ckv, 576, kv_a_ln, kvnb, 512, 512);
    // kv = kvn @ wkv_b -> bf16 — 128-tile
    cast_transpose_kernel<<<dim3(64, 8), 256, 0, stream>>>(wkv_b, wt, 512, 4096);
    gemm_bf16_kernel<<<dim3(32, 16), 256, 0, stream>>>(
        kvnb, wt, nullptr, kvbb, nullptr, nullptr, nullptr, 4096, 512);
    // RoPE
    rope_q_kernel<<<4096, 256, 0, stream>>>(qbb, cosb, sinb, pos);
    rope_kpe_kernel<<<256, 256, 0, stream>>>(ckv, kpe, cosb, sinb, pos);
    // V transpose
    vtrans_kernel<<<dim3(32, 2, 16), 256, 0, stream>>>(kvbb, vtg);
    // attention -> bf16
    attn_mfma_kernel<<<dim3(16, 16), 512, 0, stream>>>(qbb, kvbb, kpe, vtg, attb);
    // h2 = att @ wo + hidden — 256-tile split-K=4; partials z01 in gb, z23 in ub (both dead)
    cast_transpose_kernel<<<dim3(32, 32), 256, 0, stream>>>(wo, wt, 2048, 2048);
    {
        float* Pg = (float*)gb;  // 2 x 16.8 MB
        float* Pu = (float*)ub;  // 2 x 16.8 MB
        const size_t MN = (size_t)2048 * 2048;
        gemm256_kernel<<<dim3(8, 8, 4), 512, 0, stream>>>(
            attb, wt, nullptr, nullptr, nullptr, Pg, Pu, 2048, 2048);
        reduce_kernel<<<4096, 256, 0, stream>>>(
            Pg, Pg + MN, Pu, Pu + MN, hidden, h2, 1048576);
    }
    // y = rms(h2) -> bf16
    rms_kernel<<<2048, 256, 0, stream>>>(h2, 2048, post_ln, xnb, 2048, 2048);
    // gate, up -> bf16 — 256-tile (overwrite gb/ub after wo reduce)
    cast_transpose_kernel<<<dim3(128, 32), 256, 0, stream>>>(w_gate, wt, 2048, 8192);
    gemm256_kernel<<<dim3(32, 8, 1), 512, 0, stream>>>(
        xnb, wt, nullptr, gb, nullptr, nullptr, nullptr, 8192, 2048);
    cast_transpose_kernel<<<dim3(128, 32), 256, 0, stream>>>(w_up, wt, 2048, 8192);
    gemm256_kernel<<<dim3(32, 8, 1), 512, 0, stream>>>(
        xnb, wt, nullptr, ub, nullptr, nullptr, nullptr, 8192, 2048);
    // gb = silu(gb)*ub   (ub dead after this)
    silu_mul_kernel<<<8192, 256, 0, stream>>>(gb, ub, 2097152);
    // out = gb @ w_down + h2 — 256-tile split-K=4; partials z01 in ub (dead),
    // z23 in qbb..vtg span (dead since attention)
    cast_transpose_kernel<<<dim3(32, 128), 256, 0, stream>>>(w_down, wt, 8192, 2048);
    {
        float* Pu = (float*)ub;   // 2 x 16.8 MB <= 33.5 MB
        float* Pq = (float*)qbb;  // 2 x 16.8 MB <= qbb+kvbb+kpe+vtg span (38 MB)
        const size_t MN = (size_t)2048 * 2048;
        gemm256_kernel<<<dim3(8, 8, 4), 512, 0, stream>>>(
            gb, wt, nullptr, nullptr, nullptr, Pu, Pq, 2048, 8192);
        reduce_kernel<<<4096, 256, 0, stream>>>(
            Pu, Pu + MN, Pq, Pq + MN, h2, outp, 1048576);
    }
}